// Round 2
// baseline (205.389 us; speedup 1.0000x reference)
//
#include <hip/hip_runtime.h>
#include <cstdint>
#include <cstddef>

// ---------------- problem constants ----------------
#define NIMG   8
#define NPROP  2000
#define NCLS   91
#define NFG    90
#define NROW   (NIMG * NPROP)      // 16000
#define TOPK   2048
#define DETS   100
#define CKCAP  32768
#define KREGS  12                  // register-resident keys/thread (12*1024=12288)
#define BPI    125                 // blocks per image (2000 rows / 16 rows per block)

#define IMG_Wf 1333.0f
#define IMG_Hf 800.0f
#define SCORE_TH 0.05f
#define MINSZ    0.01f
#define NMS_TH   0.5f
#define CLIPV    4.135166556742356f   // log(1000/16) rounded to f32
#define ORD_NEG1 0x407FFFFFu          // ford(-1.0f)
#define PADKEY   (((ull)ORD_NEG1 << 32) | 0xFFFFFFFFull)

typedef unsigned long long ull;

// ---------------- workspace layout (bytes) ----------------
// zeroed region [0, 4096): cntv (8 counters, 256B apart) + done (8 counters, 256B apart)
static const size_t OFF_CNT  = 0;          // [0, 2048)
static const size_t OFF_DONE = 2048;       // [2048, 4096)
static const size_t OFF_VBM  = 4096;       // 16000*2*8 = 256000
static const size_t OFF_CK   = 262144;     // 8*32768*8 = 2 MiB

// ---------------- helpers ----------------
__device__ __forceinline__ unsigned ford(float f) {
    unsigned u = __float_as_uint(f);
    return (u & 0x80000000u) ? ~u : (u | 0x80000000u);
}
__device__ __forceinline__ float fordinv(unsigned x) {
    return (x & 0x80000000u) ? __uint_as_float(x & 0x7FFFFFFFu)
                             : __uint_as_float(~x);
}

// exact op-for-op mirror of reference _decode + clip (no FMA contraction)
__device__ __forceinline__ float4 decode_clip(float4 p, float4 r) {
    float w  = __fsub_rn(p.z, p.x);
    float h  = __fsub_rn(p.w, p.y);
    float cx = __fadd_rn(p.x, __fmul_rn(0.5f, w));
    float cy = __fadd_rn(p.y, __fmul_rn(0.5f, h));
    float dx = __fdiv_rn(r.x, 10.0f);
    float dy = __fdiv_rn(r.y, 10.0f);
    float dw = fminf(__fdiv_rn(r.z, 5.0f), CLIPV);
    float dh = fminf(__fdiv_rn(r.w, 5.0f), CLIPV);
    float pcx = __fadd_rn(__fmul_rn(dx, w), cx);
    float pcy = __fadd_rn(__fmul_rn(dy, h), cy);
    float pw  = __fmul_rn(expf(dw), w);
    float ph  = __fmul_rn(expf(dh), h);
    float x1 = __fsub_rn(pcx, __fmul_rn(0.5f, pw));
    float y1 = __fsub_rn(pcy, __fmul_rn(0.5f, ph));
    float x2 = __fadd_rn(pcx, __fmul_rn(0.5f, pw));
    float y2 = __fadd_rn(pcy, __fmul_rn(0.5f, ph));
    float4 o;
    o.x = fminf(fmaxf(x1, 0.0f), IMG_Wf);
    o.y = fminf(fmaxf(y1, 0.0f), IMG_Hf);
    o.z = fminf(fmaxf(x2, 0.0f), IMG_Wf);
    o.w = fminf(fmaxf(y2, 0.0f), IMG_Hf);
    return o;
}

// bitonic wave-local phase with payload: thread owns elements (base, base+1)
__device__ __forceinline__ void wl_pair(ull& a, ull& b, int& pa, int& pb,
                                        int l, int base, int k, int jmax) {
    bool desc = ((base & k) == 0);
    for (int j = jmax; j >= 2; j >>= 1) {
        int pl = l ^ (j >> 1);
        bool lower = ((base & j) == 0);
        ull qa = __shfl(a, pl), qb = __shfl(b, pl);
        int ra = __shfl(pa, pl), rb = __shfl(pb, pl);
        bool km = (desc == lower);
        bool ta = km ? (a > qa) : (a < qa);
        a = ta ? a : qa;  pa = ta ? pa : ra;
        bool tb = km ? (b > qb) : (b < qb);
        b = tb ? b : qb;  pb = tb ? pb : rb;
    }
    bool sw = ((a < b) == desc);
    if (sw) { ull t = a; a = b; b = t; int tp = pa; pa = pb; pb = tp; }
}

// ============================================================================
// Fused kernel: stage A (softmax+decode+valid -> keys) runs on all 1000 blocks;
// the LAST block to finish each image (completion counter) runs the full
// per-image pipeline: top-2048 select -> decode/bucket -> per-class NMS ->
// two-segment top-100 emit. All intermediates live in a phase-aliased LDS arena.
// Cross-XCD visibility of ck/cntv/vbm2: release = __syncthreads (drains stores
// to L2) + __threadfence (L2 writeback) before the device-scope atomicAdd;
// acquire = __threadfence (L1/L2 invalidate) after observing the final count.
// ============================================================================
__global__ __launch_bounds__(1024) void kF(const float* __restrict__ logits,
                                           const float* __restrict__ reg,
                                           const float* __restrict__ props,
                                           ull* __restrict__ ck,
                                           int* __restrict__ cntv,
                                           ull* __restrict__ vbm2,
                                           int* __restrict__ done,
                                           float* __restrict__ out) {
    // ---- LDS arena (phase-aliased; every alias separated by __syncthreads) ----
    // [0,16K)   : histw (P0/P3 radix)          | clsbox[0..1023]   (P1-P2)
    // [16K,32K) : sk (P0-P1 keys)              | clsbox[1024..2047]| kk (P3)
    // [32K,48K) : clskeyL (P1-P3)
    // [48K,56K) : rex (P0 fill path)           | ksl (P3)
    __shared__ __align__(16) char sArena[57344];
    unsigned* histw   = (unsigned*)sArena;
    float4*   clsbox  = (float4*)sArena;
    ull*      sk      = (ull*)(sArena + 16384);
    ull*      kk      = (ull*)(sArena + 16384);
    ull*      clskeyL = (ull*)(sArena + 32768);
    int*      rex     = (int*)(sArena + 49152);
    int*      ksl     = (int*)(sArena + 49152);

    __shared__ int sCnt16[32], sExc16[32];
    __shared__ int sBase, sOldv;
    __shared__ unsigned wtot4[4];
    __shared__ ull sP;
    __shared__ int sRem, sCnt, sDone, sInv, sVT, sK, sFC;
    __shared__ float sM1;
    __shared__ float sMax[16];
    __shared__ int wsum[16];
    __shared__ int ccnt[96], cplc[96], coff[96];
    __shared__ unsigned char keepb[TOPK];
    __shared__ ull fkey[128];
    __shared__ int fslot[128];

    int tid  = threadIdx.x;
    int lane = tid & 63;
    int warp = tid >> 6;

    // ================= stage A: softmax + decode + valid -> compacted keys =================
    {
        int row = blockIdx.x * 16 + warp;
        int bA  = row / NPROP;               // uniform within block
        int n   = row - bA * NPROP;
        const float* lrow = logits + (size_t)row * NCLS;

        float xa = lrow[lane];
        float xb = (lane < 27) ? lrow[64 + lane] : -INFINITY;
        float mx = fmaxf(xa, xb);
        #pragma unroll
        for (int o = 32; o; o >>= 1) mx = fmaxf(mx, __shfl_xor(mx, o));
        float ea = expf(__fsub_rn(xa, mx));
        float eb = (lane < 27) ? expf(__fsub_rn(xb, mx)) : 0.0f;
        float sden = __fadd_rn(ea, eb);
        #pragma unroll
        for (int o = 32; o; o >>= 1) sden = __fadd_rn(sden, __shfl_xor(sden, o));

        const float4 p = *reinterpret_cast<const float4*>(props + (size_t)row * 4);

        ull rowmask[2];
        bool validA[2];
        ull keyA[2];
        #pragma unroll
        for (int it = 0; it < 2; ++it) {
            int c = (it == 0) ? (1 + lane) : (65 + lane);
            bool active = (it == 0) ? true : (lane < 26);
            bool valid = false;
            ull key = 0;
            if (active) {
                float lg = lrow[c];
                float score = __fdiv_rn(expf(__fsub_rn(lg, mx)), sden);
                float4 r4 = *reinterpret_cast<const float4*>(
                    reg + ((size_t)row * NCLS + c) * 4);
                float4 bx = decode_clip(p, r4);
                float bw = __fsub_rn(bx.z, bx.x);
                float bh = __fsub_rn(bx.w, bx.y);
                valid = (score > SCORE_TH) && (bw >= MINSZ) && (bh >= MINSZ);
                int offidx = n * NFG + (c - 1);
                key = ((ull)ford(score) << 32) |
                      (ull)(0xFFFFFFFFu - (unsigned)offidx);
            }
            ull bal = __ballot(valid);
            rowmask[it] = bal;
            validA[it] = valid;
            keyA[it] = key;
            if (lane == 0) sCnt16[warp * 2 + it] = __popcll(bal);
        }
        __syncthreads();
        if (warp == 0) {
            int c = (lane < 32) ? sCnt16[lane] : 0;
            int p2 = c;
            #pragma unroll
            for (int o = 1; o < 32; o <<= 1) {
                int v = __shfl_up(p2, o);
                if (lane >= o) p2 += v;
            }
            if (lane == 31) sBase = atomicAdd(&cntv[bA * 64], p2);
            if (lane < 32) sExc16[lane] = p2 - c;
        }
        __syncthreads();
        int base = sBase;
        #pragma unroll
        for (int it = 0; it < 2; ++it) {
            if (validA[it]) {
                int slot = base + sExc16[warp * 2 + it] +
                           __popcll(rowmask[it] & ((1ull << lane) - 1ull));
                if (slot < CKCAP)
                    ck[(size_t)bA * CKCAP + slot] = keyA[it];
            }
        }
        if (lane == 0) {
            vbm2[(size_t)row * 2]     = rowmask[0];
            vbm2[(size_t)row * 2 + 1] = rowmask[1];
        }
    }

    // ================= completion handoff (last-block-finisher) =================
    int b = blockIdx.x / BPI;                // image this block belongs to
    __syncthreads();                          // all stage-A stores drained
    if (tid == 0) {
        __threadfence();                      // release: device-visible
        sOldv = atomicAdd(&done[b * 64], 1);  // device-scope
    }
    __syncthreads();
    if (sOldv != BPI - 1) return;             // uniform across block
    __threadfence();                          // acquire: every finisher thread

    // ================= P0: exact top-2048 select into sk =================
    int cnt = cntv[b * 64];
    if (cnt > CKCAP) cnt = CKCAP;
    const ull* K = ck + (size_t)b * CKCAP;

    if (cnt >= TOPK) {
        // ---- load keys into registers (coalesced, once) ----
        ull kreg[KREGS];
        #pragma unroll
        for (int r = 0; r < KREGS; ++r) {
            int i = tid + (r << 10);
            kreg[r] = (i < cnt) ? K[i] : 0ull;
        }
        // ---- 8x8-bit radix select with short-circuit (keys distinct) ----
        ull P = 0; int rem = TOPK;
        for (int pass = 7; pass >= 0; --pass) {
            int sh = pass * 8;
            *reinterpret_cast<uint4*>(&histw[tid * 4]) = make_uint4(0, 0, 0, 0);
            __syncthreads();
            ull pmask = (pass == 7) ? 0ull : (~0ull << (sh + 8));
            unsigned* hw = &histw[warp << 8];
            #pragma unroll
            for (int r = 0; r < KREGS; ++r) {
                int i = tid + (r << 10);
                if (i < cnt && (kreg[r] & pmask) == P)
                    atomicAdd(&hw[(unsigned)(kreg[r] >> sh) & 255u], 1u);
            }
            for (int i = (KREGS << 10) + tid; i < cnt; i += 1024) {   // rare tail
                ull k2 = K[i];
                if ((k2 & pmask) == P)
                    atomicAdd(&hw[(unsigned)(k2 >> sh) & 255u], 1u);
            }
            __syncthreads();
            unsigned x = 0, pfx = 0;
            if (tid < 256) {
                int d = 255 - tid;
                #pragma unroll
                for (int w = 0; w < 16; ++w) x += histw[(w << 8) + d];
                pfx = x;
                #pragma unroll
                for (int o = 1; o < 64; o <<= 1) {
                    unsigned v = __shfl_up(pfx, o);
                    if (lane >= o) pfx += v;
                }
                if (lane == 63) wtot4[tid >> 6] = pfx;
            }
            __syncthreads();
            if (tid < 256) {
                int d = 255 - tid;
                int ws2 = tid >> 6;
                unsigned add = 0;
                if (ws2 > 0) add += wtot4[0];
                if (ws2 > 1) add += wtot4[1];
                if (ws2 > 2) add += wtot4[2];
                unsigned pi   = pfx + add;    // suffixIncl(d)
                unsigned excl = pi - x;       // suffixExcl(d)
                if (x && excl < (unsigned)rem && pi >= (unsigned)rem) {
                    sP = P | ((ull)(unsigned)d << sh);
                    int nr = rem - (int)excl;
                    sRem = nr;
                    sDone = ((int)x == nr) ? 1 : 0;   // whole bin selected -> exact
                }
            }
            __syncthreads();
            P = sP; rem = sRem;
            if (sDone) break;
        }
        if (tid == 0) sCnt = 0;
        __syncthreads();
        // ---- wave-aggregated compaction from registers (unsorted) ----
        #pragma unroll
        for (int r = 0; r < KREGS; ++r) {
            int i = tid + (r << 10);
            bool sel = (i < cnt) && (kreg[r] >= P);
            ull bal = __ballot(sel);
            int cw = __popcll(bal);
            if (cw) {
                int ldr = __ffsll((long long)bal) - 1;
                int bw = 0;
                if (lane == ldr) bw = atomicAdd(&sCnt, cw);
                bw = __shfl(bw, ldr);
                if (sel) {
                    int pos = bw + __popcll(bal & ((1ull << lane) - 1ull));
                    if (pos < TOPK) sk[pos] = kreg[r];
                }
            }
        }
        for (int i = (KREGS << 10) + tid; i < cnt; i += 1024) {       // rare tail
            ull k2 = K[i];
            bool sel = (k2 >= P);
            ull bal = __ballot(sel);
            int cw = __popcll(bal);
            if (cw) {
                int ldr = __ffsll((long long)bal) - 1;
                int bw = 0;
                if (lane == ldr) bw = atomicAdd(&sCnt, cw);
                bw = __shfl(bw, ldr);
                if (sel) {
                    int pos = bw + __popcll(bal & ((1ull << lane) - 1ull));
                    if (pos < TOPK) sk[pos] = k2;
                }
            }
        }
        __syncthreads();
        int fc = sCnt;
        for (int i = fc + tid; i < TOPK; i += 1024) sk[i] = PADKEY;
    } else {
        // take all valid + fill with smallest-index invalid (score -1, ascending idx)
        for (int i = tid; i < cnt; i += 1024) sk[i] = K[i];
        int F = TOPK - cnt;
        const ull* V = vbm2 + (size_t)b * NPROP * 2;
        int r0 = 2 * tid, r1 = r0 + 1;
        int v0 = 0, v1 = 0;
        if (r0 < NPROP) v0 = NFG - __popcll(V[r0 * 2]) - __popcll(V[r0 * 2 + 1]);
        if (r1 < NPROP) v1 = NFG - __popcll(V[r1 * 2]) - __popcll(V[r1 * 2 + 1]);
        int s2 = v0 + v1;
        int pfx = s2;
        #pragma unroll
        for (int o = 1; o < 64; o <<= 1) {
            int t = __shfl_up(pfx, o);
            if (lane >= o) pfx += t;
        }
        if (lane == 63) wsum[warp] = pfx;
        __syncthreads();
        if (tid == 0) {
            int a = 0;
            for (int w = 0; w < 16; ++w) { int t = wsum[w]; wsum[w] = a; a += t; }
        }
        __syncthreads();
        int excl = pfx - s2 + wsum[warp];
        if (r0 < NPROP) rex[r0] = excl;
        if (r1 < NPROP) rex[r1] = excl + v0;
        __syncthreads();
        for (int r = tid; r < NPROP; r += 1024) {
            int e = rex[r];
            if (e < F) {
                ull m0 = V[r * 2], m1v = V[r * 2 + 1];
                int rank = e;
                ull inv = ~m0;
                while (inv && rank < F) {
                    int cb = __builtin_ctzll(inv); inv &= inv - 1;
                    unsigned idx = (unsigned)(r * NFG + cb);
                    sk[cnt + rank] = ((ull)ORD_NEG1 << 32) | (ull)(0xFFFFFFFFu - idx);
                    ++rank;
                }
                inv = (~m1v) & ((1ull << 26) - 1ull);
                while (inv && rank < F) {
                    int cb = __builtin_ctzll(inv); inv &= inv - 1;
                    unsigned idx = (unsigned)(r * NFG + 64 + cb);
                    sk[cnt + rank] = ((ull)ORD_NEG1 << 32) | (ull)(0xFFFFFFFFu - idx);
                    ++rank;
                }
            }
        }
    }
    __syncthreads();

    // ================= P1: decode 2048 + class bucketing (all in LDS) =================
    float lmax = 0.0f;
    float4 myb[2]; int myl[2]; bool vk2[2]; ull kk2[2];
    #pragma unroll
    for (int r = 0; r < 2; ++r) {
        int pos0 = tid + (r << 10);
        ull k = sk[pos0];                                  // read BEFORE clsbox overwrites
        unsigned idx = 0xFFFFFFFFu - (unsigned)(k & 0xFFFFFFFFu);
        float4 bxv;
        int n2 = (int)(idx / NFG), c2 = (int)(idx % NFG);  // label = c2+1
        int row2 = b * NPROP + n2;
        float4 p  = *reinterpret_cast<const float4*>(props + (size_t)row2 * 4);
        float4 r4 = *reinterpret_cast<const float4*>(
            reg + ((size_t)row2 * NCLS + (c2 + 1)) * 4);
        bxv = decode_clip(p, r4);
        myb[r] = bxv; myl[r] = c2 + 1; kk2[r] = k;
        vk2[r] = (((unsigned)(k >> 32)) != ORD_NEG1);
        lmax = fmaxf(lmax, fmaxf(fmaxf(bxv.x, bxv.y), fmaxf(bxv.z, bxv.w)));
    }
    #pragma unroll
    for (int o = 32; o; o >>= 1) lmax = fmaxf(lmax, __shfl_xor(lmax, o));
    if (lane == 0) sMax[warp] = lmax;
    if (tid < 96) { ccnt[tid] = 0; cplc[tid] = 0; }
    if (tid == 0) sInv = 0;
    keepb[tid] = 0; keepb[tid + 1024] = 0;
    __syncthreads();
    if (tid == 0) {
        float v = sMax[0];
        for (int i = 1; i < 16; ++i) v = fmaxf(v, sMax[i]);
        sM1 = __fadd_rn(v, 1.0f);            // jnp.max(cand_boxes) + 1.0
    }
    // phase 1: class counts
    #pragma unroll
    for (int r = 0; r < 2; ++r)
        if (vk2[r]) atomicAdd(&ccnt[myl[r] - 1], 1);
    __syncthreads();
    if (tid == 0) {
        int a = 0;
        for (int c2 = 0; c2 < NFG; ++c2) { coff[c2] = a; a += ccnt[c2]; }
        sVT = a;
    }
    __syncthreads();
    float m1 = sM1;
    int validTot = sVT;
    // phase 2: placement (order within class arbitrary; NMS sorts by key)
    #pragma unroll
    for (int r = 0; r < 2; ++r) {
        int slot;
        if (vk2[r]) {
            int cl = myl[r] - 1;
            slot = coff[cl] + atomicAdd(&cplc[cl], 1);
        } else {
            slot = validTot + atomicAdd(&sInv, 1);
        }
        float off = __fmul_rn((float)myl[r], m1);
        float4 ob;
        ob.x = __fadd_rn(myb[r].x, off);
        ob.y = __fadd_rn(myb[r].y, off);
        ob.z = __fadd_rn(myb[r].z, off);
        ob.w = __fadd_rn(myb[r].w, off);
        clsbox[slot]  = ob;            // overwrites sk bytes: all sk reads done above
        clskeyL[slot] = kk2[r];
    }
    __syncthreads();

    // ================= P2: per-(class) key-sort + greedy NMS (wave-local) =================
    {
        for (int cls = warp; cls < NFG; cls += 16) {
            int n = ccnt[cls];
            if (n <= 0) continue;
            int base2 = coff[cls];
            if (n <= 64) {
                // sort (key desc, payload slot) via shfl bitonic, pads sink (keys tiny)
                ull key = (lane < n) ? clskeyL[base2 + lane] : (ull)lane;
                int pos = (lane < n) ? (base2 + lane) : -1;
                #pragma unroll
                for (int k2 = 2; k2 <= 64; k2 <<= 1) {
                    #pragma unroll
                    for (int j = k2 >> 1; j > 0; j >>= 1) {
                        int pl = lane ^ j;
                        ull qk = __shfl(key, pl);
                        int qs = __shfl(pos, pl);
                        bool desc = ((lane & k2) == 0);
                        bool lower = ((lane & j) == 0);
                        bool km = (desc == lower);
                        bool keepown = km ? (key > qk) : (key < qk);
                        key = keepown ? key : qk;
                        pos = keepown ? pos : qs;
                    }
                }
                float4 b0 = make_float4(0.f, 0.f, 0.f, 0.f);
                float a0 = 0.0f;
                if (pos >= 0) {
                    b0 = clsbox[pos];
                    a0 = __fmul_rn(__fsub_rn(b0.z, b0.x), __fsub_rn(b0.w, b0.y));
                }
                ull alive = (n == 64) ? ~0ull : ((1ull << n) - 1ull);
                #pragma unroll 1
                for (int i = 0; i < n; ++i) {
                    if (!((alive >> i) & 1ull)) continue;
                    float bix = __shfl(b0.x, i), biy = __shfl(b0.y, i);
                    float biz = __shfl(b0.z, i), biw = __shfl(b0.w, i);
                    float ai2 = __shfl(a0, i);
                    bool sup = false;
                    if (lane < n && lane > i) {
                        float lt0 = fmaxf(bix, b0.x), lt1 = fmaxf(biy, b0.y);
                        float rb0 = fminf(biz, b0.z), rb1 = fminf(biw, b0.w);
                        float w0 = fmaxf(__fsub_rn(rb0, lt0), 0.0f);
                        float w1 = fmaxf(__fsub_rn(rb1, lt1), 0.0f);
                        float inter = __fmul_rn(w0, w1);
                        if (inter > 0.0f) {
                            float un = __fsub_rn(__fadd_rn(ai2, a0), inter);
                            sup = (__fdiv_rn(inter, un) > NMS_TH);
                        }
                    }
                    alive &= ~__ballot(sup);
                }
                if (lane < n) keepb[pos] = (unsigned char)((alive >> lane) & 1ull);
            } else {
                // barrier-free cold path (n up to 2048; statistically unreachable).
                // Greedy in key-desc order via argmax chain; per-lane alive bits
                // for strided positions j = k*64 + lane.
                unsigned aliveLoc = 0;
                #pragma unroll 1
                for (int k2 = 0; k2 < 32; ++k2) {
                    int j = (k2 << 6) + lane;
                    if (j < n) aliveLoc |= (1u << k2);
                }
                ull prevKey = ~0ull;
                while (true) {
                    ull bk = 0; int bp = -1;
                    #pragma unroll 1
                    for (int k2 = 0; k2 < 32; ++k2) {
                        if ((aliveLoc >> k2) & 1u) {
                            int j = (k2 << 6) + lane;
                            ull kj = clskeyL[base2 + j];
                            if (kj < prevKey && kj > bk) { bk = kj; bp = j; }
                        }
                    }
                    #pragma unroll
                    for (int o = 32; o; o >>= 1) {
                        ull ok = __shfl_xor(bk, o);
                        int op = __shfl_xor(bp, o);
                        if (ok > bk) { bk = ok; bp = op; }
                    }
                    if (bp < 0) break;
                    float4 bi = clsbox[base2 + bp];
                    float ai = __fmul_rn(__fsub_rn(bi.z, bi.x), __fsub_rn(bi.w, bi.y));
                    #pragma unroll 1
                    for (int k2 = 0; k2 < 32; ++k2) {
                        if ((aliveLoc >> k2) & 1u) {
                            int j = (k2 << 6) + lane;
                            ull kj = clskeyL[base2 + j];
                            if (kj < bk) {          // only lower-ranked can be suppressed
                                float4 bj = clsbox[base2 + j];
                                float aj = __fmul_rn(__fsub_rn(bj.z, bj.x),
                                                     __fsub_rn(bj.w, bj.y));
                                float lt0 = fmaxf(bi.x, bj.x), lt1 = fmaxf(bi.y, bj.y);
                                float rb0 = fminf(bi.z, bj.z), rb1 = fminf(bi.w, bj.w);
                                float w0 = fmaxf(__fsub_rn(rb0, lt0), 0.0f);
                                float w1 = fmaxf(__fsub_rn(rb1, lt1), 0.0f);
                                float inter = __fmul_rn(w0, w1);
                                if (inter > 0.0f) {
                                    float un = __fsub_rn(__fadd_rn(ai, aj), inter);
                                    if (__fdiv_rn(inter, un) > NMS_TH)
                                        aliveLoc &= ~(1u << k2);
                                }
                            }
                        }
                    }
                    prevKey = bk;
                }
                #pragma unroll 1
                for (int k2 = 0; k2 < 32; ++k2) {
                    int j = (k2 << 6) + lane;
                    if (j < n) keepb[base2 + j] = (unsigned char)((aliveLoc >> k2) & 1u);
                }
            }
        }
    }
    __syncthreads();

    // ================= P3: two-segment top-100 selection + emit =================
    {
        int emitted = 0;
        #pragma unroll 1
        for (int seg = 0; seg < 2; ++seg) {
            __syncthreads();
            if (tid == 0) sK = 0;
            __syncthreads();
            if (emitted < DETS) {
                for (int s = tid; s < TOPK; s += 1024) {
                    bool f = (seg == 0) ? (keepb[s] != 0) : (keepb[s] == 0);
                    ull key = clskeyL[s];
                    ull bal = __ballot(f);
                    int cw = __popcll(bal);
                    if (cw) {
                        int ldr = __ffsll((long long)bal) - 1;
                        int bw = 0;
                        if (lane == ldr) bw = atomicAdd(&sK, cw);
                        bw = __shfl(bw, ldr);
                        if (f) {
                            int p2 = bw + __popcll(bal & ((1ull << lane) - 1ull));
                            kk[p2] = key; ksl[p2] = s;
                        }
                    }
                }
            }
            __syncthreads();
            int K2 = sK;
            int T = DETS - emitted;
            if (T > K2) T = K2;
            if (emitted < DETS && K2 > 0) {
                ull P = 0;
                if (K2 > T) {
                    int rem = T;
                    for (int pass = 7; pass >= 0; --pass) {
                        int sh = pass * 8;
                        *reinterpret_cast<uint4*>(&histw[tid * 4]) = make_uint4(0, 0, 0, 0);
                        __syncthreads();
                        ull pmask = (pass == 7) ? 0ull : (~0ull << (sh + 8));
                        unsigned* hw = &histw[warp << 8];
                        for (int i = tid; i < K2; i += 1024) {
                            ull k2 = kk[i];
                            if ((k2 & pmask) == P)
                                atomicAdd(&hw[(unsigned)(k2 >> sh) & 255u], 1u);
                        }
                        __syncthreads();
                        unsigned x = 0, pfx = 0;
                        if (tid < 256) {
                            int d = 255 - tid;
                            #pragma unroll
                            for (int w = 0; w < 16; ++w) x += histw[(w << 8) + d];
                            pfx = x;
                            #pragma unroll
                            for (int o = 1; o < 64; o <<= 1) {
                                unsigned v = __shfl_up(pfx, o);
                                if (lane >= o) pfx += v;
                            }
                            if (lane == 63) wtot4[tid >> 6] = pfx;
                        }
                        __syncthreads();
                        if (tid < 256) {
                            int d = 255 - tid;
                            int ws2 = tid >> 6;
                            unsigned add = 0;
                            if (ws2 > 0) add += wtot4[0];
                            if (ws2 > 1) add += wtot4[1];
                            if (ws2 > 2) add += wtot4[2];
                            unsigned pi   = pfx + add;
                            unsigned excl = pi - x;
                            if (x && excl < (unsigned)rem && pi >= (unsigned)rem) {
                                sP = P | ((ull)(unsigned)d << sh);
                                int nr = rem - (int)excl;
                                sRem = nr;
                                sDone = ((int)x == nr) ? 1 : 0;
                            }
                        }
                        __syncthreads();
                        P = sP; rem = sRem;
                        if (sDone) break;
                    }
                }
                if (tid == 0) sFC = 0;
                __syncthreads();
                for (int i = tid; i < K2; i += 1024) {
                    ull k2 = kk[i];
                    bool sel = (k2 >= P);
                    ull bal = __ballot(sel);
                    int cw = __popcll(bal);
                    if (cw) {
                        int ldr = __ffsll((long long)bal) - 1;
                        int bw = 0;
                        if (lane == ldr) bw = atomicAdd(&sFC, cw);
                        bw = __shfl(bw, ldr);
                        if (sel) {
                            int p2 = bw + __popcll(bal & ((1ull << lane) - 1ull));
                            if (p2 < T) { fkey[p2] = k2; fslot[p2] = ksl[i]; }
                        }
                    }
                }
                __syncthreads();
                int FC = sFC; if (FC > T) FC = T;
                for (int i = FC + tid; i < 128; i += 1024) { fkey[i] = 0; fslot[i] = -1; }
                __syncthreads();
                if (warp == 0) {
                    int base2 = lane * 2;
                    ull a = fkey[base2], bb = fkey[base2 + 1];
                    int pa = fslot[base2], pb = fslot[base2 + 1];
                    #pragma unroll
                    for (int k2 = 2; k2 <= 128; k2 <<= 1)
                        wl_pair(a, bb, pa, pb, lane, base2, k2,
                                (k2 >> 1) < 64 ? (k2 >> 1) : 64);
                    #pragma unroll
                    for (int e = 0; e < 2; ++e) {
                        int rnk = base2 + e;
                        ull kv = e ? bb : a;
                        int sl = e ? pb : pa;
                        if (rnk < T && sl >= 0) {
                            int r2 = emitted + rnk;
                            // re-decode the winning box from its key (bit-identical ops)
                            unsigned idx = 0xFFFFFFFFu - (unsigned)(kv & 0xFFFFFFFFu);
                            int n2 = (int)(idx / NFG), c2 = (int)(idx % NFG);
                            int row2 = b * NPROP + n2;
                            float4 pp = *reinterpret_cast<const float4*>(
                                props + (size_t)row2 * 4);
                            float4 r4 = *reinterpret_cast<const float4*>(
                                reg + ((size_t)row2 * NCLS + (c2 + 1)) * 4);
                            float4 bx = decode_clip(pp, r4);
                            *reinterpret_cast<float4*>(
                                out + ((size_t)b * DETS + r2) * 4) = bx;
                            out[NIMG * DETS * 4 + b * DETS + r2] =
                                (seg == 0) ? fordinv((unsigned)(kv >> 32)) : -1.0f;
                            out[NIMG * DETS * 5 + b * DETS + r2] = (float)(c2 + 1);
                        }
                    }
                }
                emitted += T;
            }
            __syncthreads();
        }
    }
}

// ---------------- launch ----------------
extern "C" void kernel_launch(void* const* d_in, const int* in_sizes, int n_in,
                              void* d_out, int out_size, void* d_ws, size_t ws_size,
                              hipStream_t stream) {
    (void)in_sizes; (void)n_in; (void)out_size; (void)ws_size;
    const float* logits = (const float*)d_in[0];   // [16000, 91]
    const float* reg    = (const float*)d_in[1];   // [16000, 364]
    const float* props  = (const float*)d_in[2];   // [8, 2000, 4]
    float* out = (float*)d_out;                    // boxes(3200) | scores(800) | labels(800)
    char* ws = (char*)d_ws;

    int* cntv = (int*)(ws + OFF_CNT);
    int* done = (int*)(ws + OFF_DONE);
    ull* vbm2 = (ull*)(ws + OFF_VBM);
    ull* ck   = (ull*)(ws + OFF_CK);

    hipMemsetAsync(ws, 0, 4096, stream);   // zero padded cntv + done counters
    hipLaunchKernelGGL(kF, dim3(NROW / 16), dim3(1024), 0, stream,
                       logits, reg, props, ck, cntv, vbm2, done, out);
}